// Round 2
// 505.243 us; speedup vs baseline: 1.0649x; 1.0649x over previous
//
#include <hip/hip_runtime.h>

#define NN 8192
#define TILE 64

typedef float floatx4 __attribute__((ext_vector_type(4)));

// Symmetry: sym(i,j) = relu((A[i][j]+A[j][i])/2) = sym(j,i); the normalized
// output is symmetric. Only blocks with bi <= bj do work; each covers both
// the (bi,bj) and (bj,bi) output tiles.
//
// Register/LDS split: the operand consumed with the SAME (r,c) mapping it was
// loaded with stays in registers; only the transposed operand goes through
// LDS. One 64x65 tile = 17 KB -> 8 blocks/CU.

// ---------------------------------------------------------------------------
// Pass 1: rowsum[i] = sum_j sym(i,j). Block (bi<=bj) reads tiles (bi,bj)
// (registers) and (bj,bi) (LDS for transpose), emits row-sums for the bi rows
// and, via column sums, row-sums for the bj rows. Self-loop +1 in pass 2.
// ---------------------------------------------------------------------------
__global__ __launch_bounds__(256) void rowsum_kernel(const float* __restrict__ A,
                                                     float* __restrict__ rowsum) {
    const int bi = blockIdx.y, bj = blockIdx.x;
    if (bj < bi) return;                       // lower-triangle blocks idle

    __shared__ float lt[TILE][TILE + 1];       // tile (bj,bi), needs transpose
    __shared__ float cs[TILE];                 // column partial sums

    const int gi0 = bi * TILE, gj0 = bj * TILE;
    const int t  = threadIdx.x;
    const int lc = t & 15;                     // 0..15 : group of 4 columns
    const int lr = t >> 4;                     // 0..15 : row in each pass

    floatx4 va[4];                             // tile (bi,bj) rows, registers
#pragma unroll
    for (int p = 0; p < 4; ++p) {
        const int r = lr + 16 * p;
        va[p] = *(const floatx4*)&A[(size_t)(gi0 + r) * NN + gj0 + lc * 4];
        const floatx4 vb = *(const floatx4*)&A[(size_t)(gj0 + r) * NN + gi0 + lc * 4];
        lt[r][lc * 4 + 0] = vb.x; lt[r][lc * 4 + 1] = vb.y;
        lt[r][lc * 4 + 2] = vb.z; lt[r][lc * 4 + 3] = vb.w;
    }
    if (t < TILE) cs[t] = 0.0f;
    __syncthreads();

    float colpart[4] = {0.f, 0.f, 0.f, 0.f};
#pragma unroll
    for (int p = 0; p < 4; ++p) {
        const int r = lr + 16 * p;
        const float av[4] = {va[p].x, va[p].y, va[p].z, va[p].w};
        float s = 0.0f;
#pragma unroll
        for (int u = 0; u < 4; ++u) {
            const int c = lc * 4 + u;
            // lt[c][r]: stride-65 column read -> 2-way bank alias, free
            const float v = fmaxf((av[u] + lt[c][r]) * 0.5f, 0.0f);
            s += v;
            colpart[u] += v;
        }
        // row reduction across the 16 contiguous lanes sharing row r
        s += __shfl_xor(s, 1);
        s += __shfl_xor(s, 2);
        s += __shfl_xor(s, 4);
        s += __shfl_xor(s, 8);
        if (lc == 0) atomicAdd(&rowsum[gi0 + r], s);
    }

    if (bi != bj) {
        // column sums = row sums for the bj rows. Reduce colpart over the
        // 4 lr values inside this wave (lanes differ by 16, 32), then LDS.
#pragma unroll
        for (int u = 0; u < 4; ++u) {
            colpart[u] += __shfl_xor(colpart[u], 16);
            colpart[u] += __shfl_xor(colpart[u], 32);
        }
        if ((t & 48) == 0) {        // one lane per (wave, column-group)
#pragma unroll
            for (int u = 0; u < 4; ++u) atomicAdd(&cs[lc * 4 + u], colpart[u]);
        }
        __syncthreads();
        if (t < TILE) atomicAdd(&rowsum[gj0 + t], cs[t]);
    }
}

// ---------------------------------------------------------------------------
// Pass 2: out[i][j] = (sym(i,j) + (i==j)) * rinv[i] * rinv[j],
// rinv[i] = rsqrt(rowsum[i] + 1).
// Stage A: lt = tile(bj,bi); write tile (bi,bj) from va(regs) + lt^T.
// Stage B: lt = tile(bi,bj); write tile (bj,bi) from vb(regs) + lt^T.
// All out writes are NONTEMPORAL so A (exactly 256 MiB) stays L3-resident
// from pass 1 and pass 2's A reads hit the Infinity Cache instead of HBM.
// ---------------------------------------------------------------------------
__global__ __launch_bounds__(256) void normalize_kernel(const float* __restrict__ A,
                                                        const float* __restrict__ rowsum,
                                                        float* __restrict__ out) {
    const int bi = blockIdx.y, bj = blockIdx.x;
    if (bj < bi) return;

    __shared__ float lt[TILE][TILE + 1];
    __shared__ float ri[TILE];
    __shared__ float rj[TILE];

    const int gi0 = bi * TILE, gj0 = bj * TILE;
    const int t  = threadIdx.x;
    const int lc = t & 15;
    const int lr = t >> 4;

    floatx4 va[4], vb[4];
#pragma unroll
    for (int p = 0; p < 4; ++p) {
        const int r = lr + 16 * p;
        va[p] = *(const floatx4*)&A[(size_t)(gi0 + r) * NN + gj0 + lc * 4];
        vb[p] = *(const floatx4*)&A[(size_t)(gj0 + r) * NN + gi0 + lc * 4];
        lt[r][lc * 4 + 0] = vb[p].x; lt[r][lc * 4 + 1] = vb[p].y;
        lt[r][lc * 4 + 2] = vb[p].z; lt[r][lc * 4 + 3] = vb[p].w;
    }
    if (t < TILE) {
        ri[t] = rsqrtf(rowsum[gi0 + t] + 1.0f);
    } else if (t < 2 * TILE) {
        rj[t - TILE] = rsqrtf(rowsum[gj0 + t - TILE] + 1.0f);
    }
    __syncthreads();

    // ---- Stage A: tile (bi,bj), coalesced NT writes -----------------------
#pragma unroll
    for (int p = 0; p < 4; ++p) {
        const int r  = lr + 16 * p;
        const int gi = gi0 + r;
        const float av[4] = {va[p].x, va[p].y, va[p].z, va[p].w};
        floatx4 o;
#pragma unroll
        for (int u = 0; u < 4; ++u) {
            const int c  = lc * 4 + u;
            float v = fmaxf((av[u] + lt[c][r]) * 0.5f, 0.0f);
            if (gi == gj0 + c) v += 1.0f;
            o[u] = v * ri[r] * rj[c];
        }
        __builtin_nontemporal_store(o, (floatx4*)&out[(size_t)gi * NN + gj0 + lc * 4]);
    }

    // ---- Stage B: transposed tile (bj,bi), coalesced NT writes ------------
    if (bi != bj) {
        __syncthreads();                       // all stage-A lt reads done
#pragma unroll
        for (int p = 0; p < 4; ++p) {
            const int r = lr + 16 * p;
            lt[r][lc * 4 + 0] = va[p].x; lt[r][lc * 4 + 1] = va[p].y;
            lt[r][lc * 4 + 2] = va[p].z; lt[r][lc * 4 + 3] = va[p].w;
        }
        __syncthreads();
#pragma unroll
        for (int p = 0; p < 4; ++p) {
            const int r2 = lr + 16 * p;        // row within the bj tile
            const float bv[4] = {vb[p].x, vb[p].y, vb[p].z, vb[p].w};
            floatx4 o;
#pragma unroll
            for (int u = 0; u < 4; ++u) {
                const int c2 = lc * 4 + u;     // col within the bi tile
                const float v = fmaxf((bv[u] + lt[c2][r2]) * 0.5f, 0.0f);
                o[u] = v * rj[r2] * ri[c2];
            }
            __builtin_nontemporal_store(o, (floatx4*)&out[(size_t)(gj0 + r2) * NN + gi0 + lc * 4]);
        }
    }
}

extern "C" void kernel_launch(void* const* d_in, const int* in_sizes, int n_in,
                              void* d_out, int out_size, void* d_ws, size_t ws_size,
                              hipStream_t stream) {
    const float* A   = (const float*)d_in[0];
    float*       out = (float*)d_out;
    float*       rowsum = (float*)d_ws;   // NN floats = 32 KB

    (void)hipMemsetAsync(rowsum, 0, NN * sizeof(float), stream);

    dim3 grid(NN / TILE, NN / TILE);
    rowsum_kernel<<<grid, 256, 0, stream>>>(A, rowsum);
    normalize_kernel<<<grid, 256, 0, stream>>>(A, rowsum, out);
}

// Round 5
// 496.209 us; speedup vs baseline: 1.0843x; 1.0182x over previous
//
#include <hip/hip_runtime.h>

#define NN 8192
#define TILE 64
#define NB (NN / TILE)   // 128 tile rows/cols

typedef float floatx4 __attribute__((ext_vector_type(4)));

// Symmetry: sym(i,j) = relu((A[i][j]+A[j][i])/2) = sym(j,i); the normalized
// output is symmetric. Only tile pairs with bi <= bj do work; each covers
// both the (bi,bj) and (bj,bi) output tiles.
//
// L3 LIFO reuse: A is exactly 256 MiB = Infinity Cache capacity. Pass 1
// walks tiles in ascending dispatch order; pass 2 REVERSES the block->tile
// mapping so its first blocks re-read the tiles pass 1 touched last (still
// L3-resident). Pass 2's out writes are nontemporal so they don't evict A.

// ---------------------------------------------------------------------------
// Pass 1: rowsum[i] = sum_j sym(i,j). Block (bi<=bj) reads tile (bi,bj) into
// registers and tile (bj,bi) into LDS (for the transpose); emits row-sums for
// the bi rows and, via column sums, row-sums for the bj rows. Self-loop +1
// is folded into pass 2's rsqrt.
// ---------------------------------------------------------------------------
__global__ __launch_bounds__(256) void rowsum_kernel(const float* __restrict__ A,
                                                     float* __restrict__ rowsum) {
    const int bi = blockIdx.y, bj = blockIdx.x;
    if (bj < bi) return;                       // lower-triangle blocks idle

    __shared__ float lt[TILE][TILE + 1];       // tile (bj,bi), needs transpose
    __shared__ float cs[TILE];                 // column partial sums

    const int gi0 = bi * TILE, gj0 = bj * TILE;
    const int t  = threadIdx.x;
    const int lc = t & 15;                     // 0..15 : group of 4 columns
    const int lr = t >> 4;                     // 0..15 : row in each pass

    floatx4 va[4];                             // tile (bi,bj) rows, registers
#pragma unroll
    for (int p = 0; p < 4; ++p) {
        const int r = lr + 16 * p;
        va[p] = *(const floatx4*)&A[(size_t)(gi0 + r) * NN + gj0 + lc * 4];
        const floatx4 vb = *(const floatx4*)&A[(size_t)(gj0 + r) * NN + gi0 + lc * 4];
        lt[r][lc * 4 + 0] = vb.x; lt[r][lc * 4 + 1] = vb.y;
        lt[r][lc * 4 + 2] = vb.z; lt[r][lc * 4 + 3] = vb.w;
    }
    if (t < TILE) cs[t] = 0.0f;
    __syncthreads();

    float colpart[4] = {0.f, 0.f, 0.f, 0.f};
#pragma unroll
    for (int p = 0; p < 4; ++p) {
        const int r = lr + 16 * p;
        const float av[4] = {va[p].x, va[p].y, va[p].z, va[p].w};
        float s = 0.0f;
#pragma unroll
        for (int u = 0; u < 4; ++u) {
            const int c = lc * 4 + u;
            // lt[c][r]: stride-65 column read -> 2-way bank alias, free
            const float v = fmaxf((av[u] + lt[c][r]) * 0.5f, 0.0f);
            s += v;
            colpart[u] += v;
        }
        // row reduction across the 16 contiguous lanes sharing row r
        s += __shfl_xor(s, 1);
        s += __shfl_xor(s, 2);
        s += __shfl_xor(s, 4);
        s += __shfl_xor(s, 8);
        if (lc == 0) atomicAdd(&rowsum[gi0 + r], s);
    }

    if (bi != bj) {
        // column sums = row sums for the bj rows. Reduce colpart over the
        // 4 lr values inside this wave (lanes differ by 16, 32), then LDS.
#pragma unroll
        for (int u = 0; u < 4; ++u) {
            colpart[u] += __shfl_xor(colpart[u], 16);
            colpart[u] += __shfl_xor(colpart[u], 32);
        }
        if ((t & 48) == 0) {        // one lane per (wave, column-group)
#pragma unroll
            for (int u = 0; u < 4; ++u) atomicAdd(&cs[lc * 4 + u], colpart[u]);
        }
        __syncthreads();
        if (t < TILE) atomicAdd(&rowsum[gj0 + t], cs[t]);
    }
}

// ---------------------------------------------------------------------------
// Pass 2: out[i][j] = (sym(i,j) + (i==j)) * rinv[i] * rinv[j],
// rinv[i] = rsqrt(rowsum[i] + 1). Block->tile mapping is REVERSED vs pass 1
// so the first-dispatched blocks hit pass 1's most-recently-streamed (still
// L3-resident) tiles. Stage A writes tile (bi,bj); stage B restages the
// register tile through LDS and writes the transposed (bj,bi) tile, both
// with coalesced nontemporal float4 stores.
// ---------------------------------------------------------------------------
__global__ __launch_bounds__(256) void normalize_kernel(const float* __restrict__ A,
                                                        const float* __restrict__ rowsum,
                                                        float* __restrict__ out) {
    const int bi = NB - 1 - (int)blockIdx.y;   // reversed mapping
    const int bj = NB - 1 - (int)blockIdx.x;
    if (bj < bi) return;

    __shared__ float lt[TILE][TILE + 1];
    __shared__ float ri[TILE];
    __shared__ float rj[TILE];

    const int gi0 = bi * TILE, gj0 = bj * TILE;
    const int t  = threadIdx.x;
    const int lc = t & 15;
    const int lr = t >> 4;

    floatx4 va[4], vb[4];
#pragma unroll
    for (int p = 0; p < 4; ++p) {
        const int r = lr + 16 * p;
        va[p] = *(const floatx4*)&A[(size_t)(gi0 + r) * NN + gj0 + lc * 4];
        vb[p] = *(const floatx4*)&A[(size_t)(gj0 + r) * NN + gi0 + lc * 4];
        lt[r][lc * 4 + 0] = vb[p].x; lt[r][lc * 4 + 1] = vb[p].y;
        lt[r][lc * 4 + 2] = vb[p].z; lt[r][lc * 4 + 3] = vb[p].w;
    }
    if (t < TILE) {
        ri[t] = rsqrtf(rowsum[gi0 + t] + 1.0f);
    } else if (t < 2 * TILE) {
        rj[t - TILE] = rsqrtf(rowsum[gj0 + t - TILE] + 1.0f);
    }
    __syncthreads();

    // ---- Stage A: tile (bi,bj), coalesced NT writes -----------------------
#pragma unroll
    for (int p = 0; p < 4; ++p) {
        const int r  = lr + 16 * p;
        const int gi = gi0 + r;
        const float av[4] = {va[p].x, va[p].y, va[p].z, va[p].w};
        floatx4 o;
#pragma unroll
        for (int u = 0; u < 4; ++u) {
            const int c  = lc * 4 + u;
            float v = fmaxf((av[u] + lt[c][r]) * 0.5f, 0.0f);
            if (gi == gj0 + c) v += 1.0f;
            o[u] = v * ri[r] * rj[c];
        }
        __builtin_nontemporal_store(o, (floatx4*)&out[(size_t)gi * NN + gj0 + lc * 4]);
    }

    // ---- Stage B: transposed tile (bj,bi), coalesced NT writes ------------
    if (bi != bj) {
        __syncthreads();                       // all stage-A lt reads done
#pragma unroll
        for (int p = 0; p < 4; ++p) {
            const int r = lr + 16 * p;
            lt[r][lc * 4 + 0] = va[p].x; lt[r][lc * 4 + 1] = va[p].y;
            lt[r][lc * 4 + 2] = va[p].z; lt[r][lc * 4 + 3] = va[p].w;
        }
        __syncthreads();
#pragma unroll
        for (int p = 0; p < 4; ++p) {
            const int r2 = lr + 16 * p;        // row within the bj tile
            const float bv[4] = {vb[p].x, vb[p].y, vb[p].z, vb[p].w};
            floatx4 o;
#pragma unroll
            for (int u = 0; u < 4; ++u) {
                const int c2 = lc * 4 + u;     // col within the bi tile
                const float v = fmaxf((bv[u] + lt[c2][r2]) * 0.5f, 0.0f);
                o[u] = v * rj[r2] * ri[c2];
            }
            __builtin_nontemporal_store(o, (floatx4*)&out[(size_t)(gj0 + r2) * NN + gi0 + lc * 4]);
        }
    }
}

extern "C" void kernel_launch(void* const* d_in, const int* in_sizes, int n_in,
                              void* d_out, int out_size, void* d_ws, size_t ws_size,
                              hipStream_t stream) {
    const float* A   = (const float*)d_in[0];
    float*       out = (float*)d_out;
    float*       rowsum = (float*)d_ws;   // NN floats = 32 KB

    (void)hipMemsetAsync(rowsum, 0, NN * sizeof(float), stream);

    dim3 grid(NB, NB);
    rowsum_kernel<<<grid, 256, 0, stream>>>(A, rowsum);
    normalize_kernel<<<grid, 256, 0, stream>>>(A, rowsum, out);
}